// Round 3
// baseline (15820.782 us; speedup 1.0000x reference)
//
#include <hip/hip_runtime.h>
#include <stdint.h>

#define NP 100000
#define XS 280    // u16 stride of xt/pt rows: 560 B (u32 stride 140), 16B-aligned
#define HSTR 66   // u16 stride of hsb rows: 132 B (u32 stride 33 -> conflict-free)

typedef unsigned short u16;
typedef unsigned int   u32;

__device__ __forceinline__ float bf2f(u16 v) { return __uint_as_float(((u32)v) << 16); }
__device__ __forceinline__ u16 f2bf(float f) {
    u32 x = __float_as_uint(f);
    u32 r = x + 0x7fffu + ((x >> 16) & 1u);
    return (u16)(r >> 16);
}
__device__ __forceinline__ u32 packbf2(float a, float b) {
    return (u32)f2bf(a) | ((u32)f2bf(b) << 16);
}
__device__ __forceinline__ void ld8bf(const u16* p, float* x) {
    uint4 u = *reinterpret_cast<const uint4*>(p);
    x[0] = __uint_as_float(u.x << 16); x[1] = __uint_as_float(u.x & 0xffff0000u);
    x[2] = __uint_as_float(u.y << 16); x[3] = __uint_as_float(u.y & 0xffff0000u);
    x[4] = __uint_as_float(u.z << 16); x[5] = __uint_as_float(u.z & 0xffff0000u);
    x[6] = __uint_as_float(u.w << 16); x[7] = __uint_as_float(u.w & 0xffff0000u);
}
__device__ __forceinline__ void st8bf(u16* p, const float* x) {
    uint4 u;
    u.x = packbf2(x[0], x[1]); u.y = packbf2(x[2], x[3]);
    u.z = packbf2(x[4], x[5]); u.w = packbf2(x[6], x[7]);
    *reinterpret_cast<uint4*>(p) = u;
}

// ---- dtype-dual loaders ----
template<bool F32>
__device__ __forceinline__ void wpair(const void* W, int idx, float& a, float& b) {
    if constexpr (F32) {
        const float* p = (const float*)W + idx; a = p[0]; b = p[1];
    } else {
        u32 q = *reinterpret_cast<const u32*>((const u16*)W + idx);
        a = __uint_as_float(q << 16);
        b = __uint_as_float(q & 0xffff0000u);
    }
}
template<bool F32>
__device__ __forceinline__ void ldx8(const void* p, int i, float* x) {
    if constexpr (F32) {
        const float* q = (const float*)p + i;
        float4 a = *reinterpret_cast<const float4*>(q);
        float4 b = *reinterpret_cast<const float4*>(q + 4);
        x[0]=a.x; x[1]=a.y; x[2]=a.z; x[3]=a.w;
        x[4]=b.x; x[5]=b.y; x[6]=b.z; x[7]=b.w;
    } else {
        ld8bf((const u16*)p + i, x);
    }
}

// ---------------- rows-per-lane 2-layer MLP accumulate ----------------
// 64 rows/block (row = lane); 4 waves split hidden/output columns.
// colOff = first output column this wave accumulates (CW columns).
// W2 stage reads hidden 8-at-a-time (4 batched ds_read_b32) to amortize LDS latency.
template<int CIN, int H, int COUT, int CW, bool F32, bool GIN>
__device__ __forceinline__ void mlp2(const void* __restrict__ xrow,
                                     const void* __restrict__ W1, const void* __restrict__ b1,
                                     const void* __restrict__ W2,
                                     int colOff, int waveU, int lane, u16* __restrict__ hsb,
                                     float* __restrict__ acc)
{
    u16* hr = hsb + lane * HSTR;
#pragma unroll 1
    for (int h0 = 0; h0 < H; h0 += 64) {
        float hacc[16];
#pragma unroll
        for (int j = 0; j < 16; j += 2) wpair<F32>(b1, h0 + waveU * 16 + j, hacc[j], hacc[j + 1]);
#pragma unroll 1
        for (int i0 = 0; i0 < CIN; i0 += 8) {
            float x[8];
            if constexpr (GIN) ldx8<F32>(xrow, i0, x);
            else ld8bf((const u16*)xrow + i0, x);
#pragma unroll
            for (int ii = 0; ii < 8; ii++) {
                const int wb = (i0 + ii) * H + h0 + waveU * 16;
#pragma unroll
                for (int j = 0; j < 16; j += 2) {
                    float wa, wbv;
                    wpair<F32>(W1, wb + j, wa, wbv);
                    hacc[j]     = fmaf(x[ii], wa,  hacc[j]);
                    hacc[j + 1] = fmaf(x[ii], wbv, hacc[j + 1]);
                }
            }
        }
        u32* hw = (u32*)(hr + waveU * 16);
#pragma unroll
        for (int j = 0; j < 16; j += 2)
            hw[j >> 1] = packbf2(fmaxf(hacc[j], 0.f), fmaxf(hacc[j + 1], 0.f));
        __syncthreads();
        // W2: hidden chunk read 8-at-a-time (batched LDS loads, latency amortized)
        const u32* hru = (const u32*)hr;   // row base = lane*132 B, 4B-aligned
#pragma unroll 1
        for (int i0 = 0; i0 < 64; i0 += 8) {
            u32 q0 = hru[(i0 >> 1) + 0], q1 = hru[(i0 >> 1) + 1];
            u32 q2 = hru[(i0 >> 1) + 2], q3 = hru[(i0 >> 1) + 3];
            float xv[8];
            xv[0] = __uint_as_float(q0 << 16); xv[1] = __uint_as_float(q0 & 0xffff0000u);
            xv[2] = __uint_as_float(q1 << 16); xv[3] = __uint_as_float(q1 & 0xffff0000u);
            xv[4] = __uint_as_float(q2 << 16); xv[5] = __uint_as_float(q2 & 0xffff0000u);
            xv[6] = __uint_as_float(q3 << 16); xv[7] = __uint_as_float(q3 & 0xffff0000u);
#pragma unroll
            for (int ii = 0; ii < 8; ii++) {
                const int wb = (h0 + i0 + ii) * COUT + colOff;
#pragma unroll
                for (int j = 0; j < CW; j += 2) {
                    float wa, wbv;
                    wpair<F32>(W2, wb + j, wa, wbv);
                    acc[j]     = fmaf(xv[ii], wa,  acc[j]);
                    acc[j + 1] = fmaf(xv[ii], wbv, acc[j + 1]);
                }
            }
        }
        __syncthreads();
    }
}

// ---------------- LSE stage: geometry encoder + channel-softmax pool ----------------
// All 4 waves process the SAME 4 points per pass (16 passes).
// No max-subtraction in softmax (values are O(few); exp cannot overflow; softmax is
// shift-invariant) -> only 2 barriers per pass. Neighbor index software-pipelined,
// coord gathers issued at top of body to hide latency under the feature stats.
template<bool F32>
__device__ __forceinline__ void stage_phase(
    const void* __restrict__ coords, const int* __restrict__ nidx,
    const void* __restrict__ lW1, const void* __restrict__ lb1,
    const void* __restrict__ lW2, const void* __restrict__ lb2,
    int row0, int waveU, int lane,
    const u16* __restrict__ xt, u16* __restrict__ pt,
    u16* __restrict__ hsb, float* __restrict__ red)
{
    const int k = lane & 15, psub = lane >> 4;
    const int c0 = waveU * 16;   // this wave's hidden chunk
    const int e0 = waveU * 32;   // this wave's encoder-output chunk
    u16* hr = hsb + lane * HSTR; // hsb row for pair (point psub, neighbor k) == lane

    int n0 = row0 + psub; if (n0 >= NP) n0 = NP - 1;
    int jcur = nidx[(size_t)n0 * 16 + k];

#pragma unroll 1
    for (int g = 0; g < 16; g++) {
        const int pp = g * 4 + psub;
        int n = row0 + pp; if (n >= NP) n = NP - 1;

        // early: issue coord gathers for this pass (jcur was prefetched last pass)
        float ox, oy, oz, nbx, nby, nbz;
        if constexpr (F32) {
            const float* cf = (const float*)coords;
            ox = cf[n*3+0];    oy = cf[n*3+1];    oz = cf[n*3+2];
            nbx = cf[jcur*3+0]; nby = cf[jcur*3+1]; nbz = cf[jcur*3+2];
        } else {
            const u16* cb = (const u16*)coords;
            ox = bf2f(cb[n*3+0]);    oy = bf2f(cb[n*3+1]);    oz = bf2f(cb[n*3+2]);
            nbx = bf2f(cb[jcur*3+0]); nby = bf2f(cb[jcur*3+1]); nbz = bf2f(cb[jcur*3+2]);
        }
        // prefetch next pass's neighbor index
        int jnext = jcur;
        if (g < 15) {
            int nn = row0 + (g + 1) * 4 + psub; if (nn >= NP) nn = NP - 1;
            jnext = nidx[(size_t)nn * 16 + k];
        }

        // feature-half stats (8 channels per k-lane; butterflies over the 16 k-lanes)
        float f8[8];
        ld8bf(xt + pp * XS + k * 8, f8);
        float ef[8], F = 0.f;
#pragma unroll
        for (int q = 0; q < 8; q++) { ef[q] = __expf(f8[q]); F += ef[q]; }
#pragma unroll
        for (int m = 1; m <= 8; m <<= 1) F += __shfl_xor(F, m, 16);

        float rx = ox - nbx, ry = oy - nby, rz = oz - nbz;
        float dd = sqrtf(rx*rx + ry*ry + rz*rz);
        float v[10] = {ox,oy,oz,nbx,nby,nbz,rx,ry,rz,dd};

        // layer1: this wave computes hidden[c0..c0+16) for its (k,psub) pair.
        {
            float hh[16];
#pragma unroll
            for (int jj = 0; jj < 16; jj += 2) wpair<F32>(lb1, c0 + jj, hh[jj], hh[jj+1]);
#pragma unroll
            for (int i = 0; i < 10; i++) {
#pragma unroll
                for (int jj = 0; jj < 16; jj += 2) {
                    float wa, wb2; wpair<F32>(lW1, i * 64 + c0 + jj, wa, wb2);
                    hh[jj]     = fmaf(v[i], wa,  hh[jj]);
                    hh[jj + 1] = fmaf(v[i], wb2, hh[jj + 1]);
                }
            }
            u32* hw = (u32*)(hr + c0);
#pragma unroll
            for (int jj = 0; jj < 16; jj += 2)
                hw[jj >> 1] = packbf2(fmaxf(hh[jj], 0.f), fmaxf(hh[jj + 1], 0.f));
        }
        __syncthreads();   // S1: hidden complete in hsb

        // layer2: 64 -> 32 (channels e0..e0+32), hidden read 8-at-a-time
        float e[32];
#pragma unroll
        for (int jj = 0; jj < 32; jj += 2) wpair<F32>(lb2, e0 + jj, e[jj], e[jj+1]);
        const u32* hru = (const u32*)hr;
#pragma unroll 1
        for (int i0 = 0; i0 < 64; i0 += 8) {
            u32 q0 = hru[(i0 >> 1) + 0], q1 = hru[(i0 >> 1) + 1];
            u32 q2 = hru[(i0 >> 1) + 2], q3 = hru[(i0 >> 1) + 3];
            float xv[8];
            xv[0] = __uint_as_float(q0 << 16); xv[1] = __uint_as_float(q0 & 0xffff0000u);
            xv[2] = __uint_as_float(q1 << 16); xv[3] = __uint_as_float(q1 & 0xffff0000u);
            xv[4] = __uint_as_float(q2 << 16); xv[5] = __uint_as_float(q2 & 0xffff0000u);
            xv[6] = __uint_as_float(q3 << 16); xv[7] = __uint_as_float(q3 & 0xffff0000u);
#pragma unroll
            for (int ii = 0; ii < 8; ii++) {
                const int wb0 = (i0 + ii) * 128 + e0;
#pragma unroll
                for (int jj = 0; jj < 32; jj += 2) {
                    float wa, wb2;
                    wpair<F32>(lW2, wb0 + jj, wa, wb2);
                    e[jj]     = fmaf(xv[ii], wa,  e[jj]);
                    e[jj + 1] = fmaf(xv[ii], wb2, e[jj + 1]);
                }
            }
        }

        // channel-softmax (no shift): per-wave partial sum of exp over its 32 channels
        float s = 0.f;
#pragma unroll
        for (int c = 0; c < 32; c++) { float t = __expf(e[c]); s += t; e[c] *= t; }
        red[waveU * 64 + lane] = s;
        __syncthreads();   // S2
        float stot = red[lane] + red[64 + lane] + red[128 + lane] + red[192 + lane] + F;
        float inv = 1.0f / stot;
        float T = inv;
#pragma unroll
        for (int c = 0; c < 32; c++) e[c] *= inv;

        // reduce over k (16-lane butterflies)
#pragma unroll
        for (int m = 1; m <= 8; m <<= 1) {
#pragma unroll
            for (int c = 0; c < 32; c++) e[c] += __shfl_xor(e[c], m, 16);
            T += __shfl_xor(T, m, 16);
        }

        u16* prow = pt + pp * XS;
        if (k == 0) {
#pragma unroll
            for (int c = 0; c < 32; c += 8) st8bf(prow + e0 + c, e + c);
        }
        if (waveU == 0) {
            float pf[8];
#pragma unroll
            for (int q = 0; q < 8; q++) pf[q] = ef[q] * f8[q] * T;
            st8bf(prow + 128 + k * 8, pf);
        }
        jcur = jnext;
    }
}

// ---------------- the fused per-point network ----------------
struct WPtrs { const void* p[28]; };

template<bool F32>
__device__ __forceinline__ void run_all(
    const void* __restrict__ coords, const void* __restrict__ feats,
    const int* __restrict__ nidx, const WPtrs& wp, void* __restrict__ outp,
    u16* __restrict__ xt, u16* __restrict__ pt, u16* __restrict__ hsb,
    float* __restrict__ red)
{
    const int waveU = __builtin_amdgcn_readfirstlane((int)(threadIdx.x >> 6));
    const int lane  = threadIdx.x & 63;
    const int row0  = blockIdx.x * 64;
    int rowL = row0 + lane; if (rowL >= NP) rowL = NP - 1;
    const void* frow = F32 ? (const void*)((const float*)feats + (size_t)rowL * 128)
                           : (const void*)((const u16*)feats + (size_t)rowL * 128);

    // phase 1: mlp1 (128 -> 128 -> 128) -> xt[:,0:128)
    {
        float acc[32];
#pragma unroll
        for (int j = 0; j < 32; j += 2) wpair<F32>(wp.p[3], waveU * 32 + j, acc[j], acc[j + 1]);
        mlp2<128,128,128,32,F32,true>(frow, wp.p[0], wp.p[1], wp.p[2], waveU * 32, waveU, lane, hsb, acc);
        u16* xr = xt + lane * XS + waveU * 32;
#pragma unroll
        for (int t = 0; t < 32; t += 8) st8bf(xr + t, acc + t);
    }
    __syncthreads();

    // phase 2: lse1 + pool numerators -> pt[:,0:256)
    stage_phase<F32>(coords, nidx, wp.p[12], wp.p[13], wp.p[14], wp.p[15],
                     row0, waveU, lane, xt, pt, hsb, red);
    __syncthreads();

    // phase 3: pool1 mlp (256 -> 256 -> 128) -> xt[:,0:128)
    {
        float acc[32];
#pragma unroll
        for (int j = 0; j < 32; j += 2) wpair<F32>(wp.p[23], waveU * 32 + j, acc[j], acc[j + 1]);
        mlp2<256,256,128,32,F32,false>(pt + lane * XS, wp.p[20], wp.p[21], wp.p[22], waveU * 32, waveU, lane, hsb, acc);
        u16* xr = xt + lane * XS + waveU * 32;
#pragma unroll
        for (int t = 0; t < 32; t += 8) st8bf(xr + t, acc + t);
    }
    __syncthreads();

    // phase 4: lse2 -> pt
    stage_phase<F32>(coords, nidx, wp.p[16], wp.p[17], wp.p[18], wp.p[19],
                     row0, waveU, lane, xt, pt, hsb, red);
    __syncthreads();

    // phase 5: pool2 mlp (256 -> 256 -> 256) -> xt[:,0:256)
    {
        float acc[64];
#pragma unroll
        for (int j = 0; j < 64; j += 2) wpair<F32>(wp.p[27], waveU * 64 + j, acc[j], acc[j + 1]);
        mlp2<256,256,256,64,F32,false>(pt + lane * XS, wp.p[24], wp.p[25], wp.p[26], waveU * 64, waveU, lane, hsb, acc);
        u16* xr = xt + lane * XS + waveU * 64;
#pragma unroll
        for (int t = 0; t < 64; t += 8) st8bf(xr + t, acc + t);
    }
    __syncthreads();

    // phase 6: leaky(m2(xt) + m3(feats)) -> out
    // Two column passes of 64 (acc[64]) instead of one pass of 128: peak register
    // demand fits the 128-VGPR allocation -> no scratch spills. W1 stages recomputed
    // per pass (+13% FLOPs), W2 accumulation split by columns.
#pragma unroll 1
    for (int p = 0; p < 2; p++) {
        const int colOff = waveU * 128 + p * 64;
        float acc[64];
#pragma unroll
        for (int j = 0; j < 64; j += 2) {
            float a2a, a2b, a3a, a3b;
            wpair<F32>(wp.p[7],  colOff + j, a2a, a2b);
            wpair<F32>(wp.p[11], colOff + j, a3a, a3b);
            acc[j] = a2a + a3a; acc[j + 1] = a2b + a3b;
        }
        mlp2<256,384,512,64,F32,false>(xt + lane * XS, wp.p[4], wp.p[5], wp.p[6], colOff, waveU, lane, hsb, acc);
        mlp2<128,256,512,64,F32,true >(frow, wp.p[8], wp.p[9], wp.p[10], colOff, waveU, lane, hsb, acc);
        if (row0 + lane < NP) {
            const size_t ob = (size_t)(row0 + lane) * 512 + colOff;
            if constexpr (F32) {
                float* orow = (float*)outp + ob;
#pragma unroll
                for (int j = 0; j < 64; j += 4) {
                    float r[4];
#pragma unroll
                    for (int q = 0; q < 4; q++) { float vv = acc[j + q]; r[q] = vv > 0.f ? vv : 0.01f * vv; }
                    *reinterpret_cast<float4*>(orow + j) = make_float4(r[0], r[1], r[2], r[3]);
                }
            } else {
                u16* orow = (u16*)outp + ob;
#pragma unroll
                for (int j = 0; j < 64; j += 8) {
                    float r[8];
#pragma unroll
                    for (int q = 0; q < 8; q++) { float vv = acc[j + q]; r[q] = vv > 0.f ? vv : 0.01f * vv; }
                    st8bf(orow + j, r);
                }
            }
        }
    }
}

__global__ __launch_bounds__(256)
__attribute__((amdgpu_waves_per_eu(2, 2)))
void k_mega(
    const void* __restrict__ coords, const void* __restrict__ feats,
    const int* __restrict__ nidx, WPtrs wp, void* __restrict__ outp)
{
    __shared__ __align__(16) u16 xt[64 * XS];
    __shared__ __align__(16) u16 pt[64 * XS];
    __shared__ __align__(16) u16 hsb[64 * HSTR];
    __shared__ __align__(16) float red[256];   // cross-wave softmax reduce (1KB)
    __shared__ int sflag;

    // per-block dtype detection: bf16-interpret the first 128 u16 of coords.
    if (threadIdx.x == 0) {
        const u16* c16 = (const u16*)coords;
        int bad = 0;
        for (int i = 0; i < 128; i++) {
            u32 e = (c16[i] >> 7) & 0xFFu;
            bad += (e != 0u && (e < 63u || e > 191u)) ? 1 : 0;
        }
        sflag = bad;
    }
    __syncthreads();

    if (sflag) run_all<true >(coords, feats, nidx, wp, outp, xt, pt, hsb, red);
    else       run_all<false>(coords, feats, nidx, wp, outp, xt, pt, hsb, red);
}

// ---------------- host ----------------
extern "C" void kernel_launch(void* const* d_in, const int* in_sizes, int n_in,
                              void* d_out, int out_size, void* d_ws, size_t ws_size,
                              hipStream_t stream)
{
    const void* coords = d_in[0];
    const void* feats  = d_in[1];
    const int*  nidx   = (const int*)d_in[2];

    WPtrs wp;
    for (int i = 0; i < 28; i++) wp.p[i] = d_in[3 + i];
    // p[0..3]=m1, p[4..7]=m2, p[8..11]=m3, p[12..15]=l1, p[16..19]=l2, p[20..23]=p1, p[24..27]=p2

    k_mega<<<(NP + 63) / 64, 256, 0, stream>>>(coords, feats, nidx, wp, d_out);
}

// Round 4
// 9688.264 us; speedup vs baseline: 1.6330x; 1.6330x over previous
//
#include <hip/hip_runtime.h>
#include <stdint.h>

#define NP 100000
#define XS 280    // u16 stride of xt/pt rows: 560 B (u32 stride 140), 16B-aligned
#define HSTR 66   // u16 stride of hsb rows: 132 B (u32 stride 33 -> conflict-free)

typedef unsigned short u16;
typedef unsigned int   u32;

__device__ __forceinline__ float bf2f(u16 v) { return __uint_as_float(((u32)v) << 16); }
__device__ __forceinline__ u16 f2bf(float f) {
    u32 x = __float_as_uint(f);
    u32 r = x + 0x7fffu + ((x >> 16) & 1u);
    return (u16)(r >> 16);
}
__device__ __forceinline__ u32 packbf2(float a, float b) {
    return (u32)f2bf(a) | ((u32)f2bf(b) << 16);
}
__device__ __forceinline__ void ld8bf(const u16* p, float* x) {
    uint4 u = *reinterpret_cast<const uint4*>(p);
    x[0] = __uint_as_float(u.x << 16); x[1] = __uint_as_float(u.x & 0xffff0000u);
    x[2] = __uint_as_float(u.y << 16); x[3] = __uint_as_float(u.y & 0xffff0000u);
    x[4] = __uint_as_float(u.z << 16); x[5] = __uint_as_float(u.z & 0xffff0000u);
    x[6] = __uint_as_float(u.w << 16); x[7] = __uint_as_float(u.w & 0xffff0000u);
}
__device__ __forceinline__ void st8bf(u16* p, const float* x) {
    uint4 u;
    u.x = packbf2(x[0], x[1]); u.y = packbf2(x[2], x[3]);
    u.z = packbf2(x[4], x[5]); u.w = packbf2(x[6], x[7]);
    *reinterpret_cast<uint4*>(p) = u;
}

// ---- dtype-dual loaders ----
template<bool F32>
__device__ __forceinline__ void wpair(const void* W, int idx, float& a, float& b) {
    if constexpr (F32) {
        const float* p = (const float*)W + idx; a = p[0]; b = p[1];
    } else {
        u32 q = *reinterpret_cast<const u32*>((const u16*)W + idx);
        a = __uint_as_float(q << 16);
        b = __uint_as_float(q & 0xffff0000u);
    }
}
template<bool F32>
__device__ __forceinline__ float wld(const void* W, int idx) {
    if constexpr (F32) return ((const float*)W)[idx];
    else return bf2f(((const u16*)W)[idx]);
}
template<bool F32>
__device__ __forceinline__ void ldx8(const void* p, int i, float* x) {
    if constexpr (F32) {
        const float* q = (const float*)p + i;
        float4 a = *reinterpret_cast<const float4*>(q);
        float4 b = *reinterpret_cast<const float4*>(q + 4);
        x[0]=a.x; x[1]=a.y; x[2]=a.z; x[3]=a.w;
        x[4]=b.x; x[5]=b.y; x[6]=b.z; x[7]=b.w;
    } else {
        ld8bf((const u16*)p + i, x);
    }
}

// ---------------- rows-per-lane 2-layer MLP accumulate (round-2 version) ---------
// 64 rows/block (row = lane); 4 waves split hidden/output columns.
template<int CIN, int H, int COUT, int CW, bool F32, bool GIN>
__device__ __forceinline__ void mlp2(const void* __restrict__ xrow,
                                     const void* __restrict__ W1, const void* __restrict__ b1,
                                     const void* __restrict__ W2,
                                     int waveU, int lane, u16* __restrict__ hsb,
                                     float* __restrict__ acc)
{
    u16* hr = hsb + lane * HSTR;
#pragma unroll 1
    for (int h0 = 0; h0 < H; h0 += 64) {
        float hacc[16];
#pragma unroll
        for (int j = 0; j < 16; j += 2) wpair<F32>(b1, h0 + waveU * 16 + j, hacc[j], hacc[j + 1]);
#pragma unroll 1
        for (int i0 = 0; i0 < CIN; i0 += 8) {
            float x[8];
            if constexpr (GIN) ldx8<F32>(xrow, i0, x);
            else ld8bf((const u16*)xrow + i0, x);
#pragma unroll
            for (int ii = 0; ii < 8; ii++) {
                const int wb = (i0 + ii) * H + h0 + waveU * 16;
#pragma unroll
                for (int j = 0; j < 16; j += 2) {
                    float wa, wbv;
                    wpair<F32>(W1, wb + j, wa, wbv);
                    hacc[j]     = fmaf(x[ii], wa,  hacc[j]);
                    hacc[j + 1] = fmaf(x[ii], wbv, hacc[j + 1]);
                }
            }
        }
        u32* hw = (u32*)(hr + waveU * 16);
#pragma unroll
        for (int j = 0; j < 16; j += 2)
            hw[j >> 1] = packbf2(fmaxf(hacc[j], 0.f), fmaxf(hacc[j + 1], 0.f));
        __syncthreads();
#pragma unroll 1
        for (int i = 0; i < 64; i++) {
            float xv = bf2f(hr[i]);
            const int wb = (h0 + i) * COUT + waveU * CW;
#pragma unroll
            for (int j = 0; j < CW; j += 2) {
                float wa, wbv;
                wpair<F32>(W2, wb + j, wa, wbv);
                acc[j]     = fmaf(xv, wa,  acc[j]);
                acc[j + 1] = fmaf(xv, wbv, acc[j + 1]);
            }
        }
        __syncthreads();
    }
}

// ---------------- LSE stage (round-3 version: shift-free softmax, 2 barriers) ----
template<bool F32>
__device__ __forceinline__ void stage_phase(
    const void* __restrict__ coords, const int* __restrict__ nidx,
    const void* __restrict__ lW1, const void* __restrict__ lb1,
    const void* __restrict__ lW2, const void* __restrict__ lb2,
    int row0, int waveU, int lane,
    const u16* __restrict__ xt, u16* __restrict__ pt,
    u16* __restrict__ hsb, float* __restrict__ red)
{
    const int k = lane & 15, psub = lane >> 4;
    const int c0 = waveU * 16;   // this wave's hidden chunk
    const int e0 = waveU * 32;   // this wave's encoder-output chunk
    u16* hr = hsb + lane * HSTR;

    int n0 = row0 + psub; if (n0 >= NP) n0 = NP - 1;
    int jcur = nidx[(size_t)n0 * 16 + k];

#pragma unroll 1
    for (int g = 0; g < 16; g++) {
        const int pp = g * 4 + psub;
        int n = row0 + pp; if (n >= NP) n = NP - 1;

        float ox, oy, oz, nbx, nby, nbz;
        if constexpr (F32) {
            const float* cf = (const float*)coords;
            ox = cf[n*3+0];    oy = cf[n*3+1];    oz = cf[n*3+2];
            nbx = cf[jcur*3+0]; nby = cf[jcur*3+1]; nbz = cf[jcur*3+2];
        } else {
            const u16* cb = (const u16*)coords;
            ox = bf2f(cb[n*3+0]);    oy = bf2f(cb[n*3+1]);    oz = bf2f(cb[n*3+2]);
            nbx = bf2f(cb[jcur*3+0]); nby = bf2f(cb[jcur*3+1]); nbz = bf2f(cb[jcur*3+2]);
        }
        int jnext = jcur;
        if (g < 15) {
            int nn = row0 + (g + 1) * 4 + psub; if (nn >= NP) nn = NP - 1;
            jnext = nidx[(size_t)nn * 16 + k];
        }

        float f8[8];
        ld8bf(xt + pp * XS + k * 8, f8);
        float ef[8], F = 0.f;
#pragma unroll
        for (int q = 0; q < 8; q++) { ef[q] = __expf(f8[q]); F += ef[q]; }
#pragma unroll
        for (int m = 1; m <= 8; m <<= 1) F += __shfl_xor(F, m, 16);

        float rx = ox - nbx, ry = oy - nby, rz = oz - nbz;
        float dd = sqrtf(rx*rx + ry*ry + rz*rz);
        float v[10] = {ox,oy,oz,nbx,nby,nbz,rx,ry,rz,dd};

        {
            float hh[16];
#pragma unroll
            for (int jj = 0; jj < 16; jj += 2) wpair<F32>(lb1, c0 + jj, hh[jj], hh[jj+1]);
#pragma unroll
            for (int i = 0; i < 10; i++) {
#pragma unroll
                for (int jj = 0; jj < 16; jj += 2) {
                    float wa, wb2; wpair<F32>(lW1, i * 64 + c0 + jj, wa, wb2);
                    hh[jj]     = fmaf(v[i], wa,  hh[jj]);
                    hh[jj + 1] = fmaf(v[i], wb2, hh[jj + 1]);
                }
            }
            u32* hw = (u32*)(hr + c0);
#pragma unroll
            for (int jj = 0; jj < 16; jj += 2)
                hw[jj >> 1] = packbf2(fmaxf(hh[jj], 0.f), fmaxf(hh[jj + 1], 0.f));
        }
        __syncthreads();   // S1: hidden complete in hsb

        float e[32];
#pragma unroll
        for (int jj = 0; jj < 32; jj += 2) wpair<F32>(lb2, e0 + jj, e[jj], e[jj+1]);
#pragma unroll 1
        for (int i = 0; i < 64; i += 2) {
            u32 hq = *reinterpret_cast<const u32*>(hr + i);
            float x0 = __uint_as_float(hq << 16);
            float x1 = __uint_as_float(hq & 0xffff0000u);
            const int wb0 = i * 128 + e0;
#pragma unroll
            for (int jj = 0; jj < 32; jj += 2) {
                float wa, wb2;
                wpair<F32>(lW2, wb0 + jj, wa, wb2);
                e[jj]     = fmaf(x0, wa,  e[jj]);
                e[jj + 1] = fmaf(x0, wb2, e[jj + 1]);
                wpair<F32>(lW2, wb0 + 128 + jj, wa, wb2);
                e[jj]     = fmaf(x1, wa,  e[jj]);
                e[jj + 1] = fmaf(x1, wb2, e[jj + 1]);
            }
        }

        float s = 0.f;
#pragma unroll
        for (int c = 0; c < 32; c++) { float t = __expf(e[c]); s += t; e[c] *= t; }
        red[waveU * 64 + lane] = s;
        __syncthreads();   // S2
        float stot = red[lane] + red[64 + lane] + red[128 + lane] + red[192 + lane] + F;
        float inv = 1.0f / stot;
        float T = inv;
#pragma unroll
        for (int c = 0; c < 32; c++) e[c] *= inv;

#pragma unroll
        for (int m = 1; m <= 8; m <<= 1) {
#pragma unroll
            for (int c = 0; c < 32; c++) e[c] += __shfl_xor(e[c], m, 16);
            T += __shfl_xor(T, m, 16);
        }

        u16* prow = pt + pp * XS;
        if (k == 0) {
#pragma unroll
            for (int c = 0; c < 32; c += 8) st8bf(prow + e0 + c, e + c);
        }
        if (waveU == 0) {
            float pf[8];
#pragma unroll
            for (int q = 0; q < 8; q++) pf[q] = ef[q] * f8[q] * T;
            st8bf(prow + 128 + k * 8, pf);
        }
        jcur = jnext;
    }
}

// ---------------- the fused per-point network ----------------
struct WPtrs { const void* p[28]; };

template<bool F32>
__device__ __forceinline__ void run_all(
    const void* __restrict__ coords, const void* __restrict__ feats,
    const int* __restrict__ nidx, const WPtrs& wp, void* __restrict__ outp,
    u16* __restrict__ xt, u16* __restrict__ pt, u16* __restrict__ hsb,
    float* __restrict__ red)
{
    const int waveU = __builtin_amdgcn_readfirstlane((int)(threadIdx.x >> 6));
    const int lane  = threadIdx.x & 63;
    const int row0  = blockIdx.x * 64;
    int rowL = row0 + lane; if (rowL >= NP) rowL = NP - 1;
    const void* frow = F32 ? (const void*)((const float*)feats + (size_t)rowL * 128)
                           : (const void*)((const u16*)feats + (size_t)rowL * 128);

    // phase 1: mlp1 (128 -> 128 -> 128) -> xt[:,0:128)
    {
        float acc[32];
#pragma unroll
        for (int j = 0; j < 32; j += 2) wpair<F32>(wp.p[3], waveU * 32 + j, acc[j], acc[j + 1]);
        mlp2<128,128,128,32,F32,true>(frow, wp.p[0], wp.p[1], wp.p[2], waveU, lane, hsb, acc);
        u16* xr = xt + lane * XS + waveU * 32;
#pragma unroll
        for (int t = 0; t < 32; t += 8) st8bf(xr + t, acc + t);
    }
    __syncthreads();

    // phase 2: lse1 + pool numerators -> pt[:,0:256)
    stage_phase<F32>(coords, nidx, wp.p[12], wp.p[13], wp.p[14], wp.p[15],
                     row0, waveU, lane, xt, pt, hsb, red);
    __syncthreads();

    // phase 3: pool1 mlp (256 -> 256 -> 128) -> xt[:,0:128)
    {
        float acc[32];
#pragma unroll
        for (int j = 0; j < 32; j += 2) wpair<F32>(wp.p[23], waveU * 32 + j, acc[j], acc[j + 1]);
        mlp2<256,256,128,32,F32,false>(pt + lane * XS, wp.p[20], wp.p[21], wp.p[22], waveU, lane, hsb, acc);
        u16* xr = xt + lane * XS + waveU * 32;
#pragma unroll
        for (int t = 0; t < 32; t += 8) st8bf(xr + t, acc + t);
    }
    __syncthreads();

    // phase 4: lse2 -> pt
    stage_phase<F32>(coords, nidx, wp.p[16], wp.p[17], wp.p[18], wp.p[19],
                     row0, waveU, lane, xt, pt, hsb, red);
    __syncthreads();

    // phase 5: pool2 mlp (256 -> 256 -> 256) -> xt[:,0:256)
    {
        float acc[64];
#pragma unroll
        for (int j = 0; j < 64; j += 2) wpair<F32>(wp.p[27], waveU * 64 + j, acc[j], acc[j + 1]);
        mlp2<256,256,256,64,F32,false>(pt + lane * XS, wp.p[24], wp.p[25], wp.p[26], waveU, lane, hsb, acc);
        u16* xr = xt + lane * XS + waveU * 64;
#pragma unroll
        for (int t = 0; t < 64; t += 8) st8bf(xr + t, acc + t);
    }
    __syncthreads();

    // ---------------- phase 6 (col-per-lane, LDS-staged hidden) ----------------
    // out[r][c] = leaky(m2(xt_r)[c] + m3(feat_r)[c]).  lane = output column ->
    // weights are per-lane COALESCED VECTOR loads (vmcnt-pipelined), activations
    // are wave-uniform LDS broadcast reads. No SMEM serialization, no >64-wide
    // accumulators (rows processed in halves of 32 -> acc[32]x2 per lane).
    // pt region reused: m2 hidden 32x384 bf16 (24.5 KB) / m3 hidden 32x256 bf16
    // (16 KB) + staged feats 32x128 (16 KB f32 or 8 KB bf16).
    {
        const int colA = waveU * 128 + lane;
        const int colB = colA + 64;
        const float bA = wld<F32>(wp.p[7], colA) + wld<F32>(wp.p[11], colA);
        const float bB = wld<F32>(wp.p[7], colB) + wld<F32>(wp.p[11], colB);
        u16* hidb = pt;                               // hidden stage (bf16)
        void* ftbv = (void*)(pt + 8192);              // feats stage (native dtype), byte off 16384
        const int rbase = waveU * 8;                  // this wave's local row group

#pragma unroll 1
        for (int rh = 0; rh < 64; rh += 32) {
            // A) m2 hidden: relu(xt[rh..rh+32) x m2_W1 + b1) -> hidb[32][384]
#pragma unroll 1
            for (int c = 0; c < 6; c++) {
                const int hcol = c * 64 + lane;
                const float bb = wld<F32>(wp.p[5], hcol);
                float a[8];
#pragma unroll
                for (int r = 0; r < 8; r++) a[r] = bb;
#pragma unroll 1
                for (int i0 = 0; i0 < 256; i0 += 8) {
                    float w8[8];
#pragma unroll
                    for (int j = 0; j < 8; j++) w8[j] = wld<F32>(wp.p[4], (i0 + j) * 384 + hcol);
#pragma unroll
                    for (int r = 0; r < 8; r++) {
                        float x8[8];
                        ld8bf(xt + (rh + rbase + r) * XS + i0, x8);
#pragma unroll
                        for (int j = 0; j < 8; j++) a[r] = fmaf(x8[j], w8[j], a[r]);
                    }
                }
                u16* hw = hidb + rbase * 384 + hcol;
#pragma unroll
                for (int r = 0; r < 8; r++) hw[r * 384] = f2bf(fmaxf(a[r], 0.f));
            }
            __syncthreads();   // hid(m2) ready

            // B) W2-m2 accumulate: acc[32] x 2 cols
            float accA[32], accB[32];
#pragma unroll
            for (int r = 0; r < 32; r++) { accA[r] = bA; accB[r] = bB; }
#pragma unroll 1
            for (int h0 = 0; h0 < 384; h0 += 8) {
                float wA[8], wB[8];
#pragma unroll
                for (int j = 0; j < 8; j++) {
                    const int wb = (h0 + j) * 512;
                    wA[j] = wld<F32>(wp.p[6], wb + colA);
                    wB[j] = wld<F32>(wp.p[6], wb + colB);
                }
#pragma unroll
                for (int r = 0; r < 32; r++) {
                    float x8[8];
                    ld8bf(hidb + r * 384 + h0, x8);
#pragma unroll
                    for (int j = 0; j < 8; j++) {
                        accA[r] = fmaf(x8[j], wA[j], accA[r]);
                        accB[r] = fmaf(x8[j], wB[j], accB[r]);
                    }
                }
            }
            __syncthreads();   // hid(m2) consumed, region reusable

            // C) stage feats rows [rh..rh+32) into ftbv (native dtype)
            {
                const int t = (int)threadIdx.x;
                const int r = t >> 3, cc = (t & 7) * 16;
                int rg = row0 + rh + r; if (rg >= NP) rg = NP - 1;
                if constexpr (F32) {
                    const float* src = (const float*)feats + (size_t)rg * 128 + cc;
                    float* dst = (float*)ftbv + r * 128 + cc;
#pragma unroll
                    for (int q = 0; q < 16; q += 4)
                        *reinterpret_cast<float4*>(dst + q) = *reinterpret_cast<const float4*>(src + q);
                } else {
                    const u16* src = (const u16*)feats + (size_t)rg * 128 + cc;
                    u16* dst = (u16*)ftbv + r * 128 + cc;
#pragma unroll
                    for (int q = 0; q < 16; q += 8)
                        *reinterpret_cast<uint4*>(dst + q) = *reinterpret_cast<const uint4*>(src + q);
                }
            }
            __syncthreads();   // feats staged

            // D) m3 hidden: relu(feats x m3_W1 + b1) -> hidb[32][256]
#pragma unroll 1
            for (int c = 0; c < 4; c++) {
                const int hcol = c * 64 + lane;
                const float bb = wld<F32>(wp.p[9], hcol);
                float a[8];
#pragma unroll
                for (int r = 0; r < 8; r++) a[r] = bb;
#pragma unroll 1
                for (int i0 = 0; i0 < 128; i0 += 8) {
                    float w8[8];
#pragma unroll
                    for (int j = 0; j < 8; j++) w8[j] = wld<F32>(wp.p[8], (i0 + j) * 256 + hcol);
#pragma unroll
                    for (int r = 0; r < 8; r++) {
                        float x8[8];
                        ldx8<F32>(ftbv, (rbase + r) * 128 + i0, x8);
#pragma unroll
                        for (int j = 0; j < 8; j++) a[r] = fmaf(x8[j], w8[j], a[r]);
                    }
                }
                u16* hw = hidb + rbase * 256 + hcol;
#pragma unroll
                for (int r = 0; r < 8; r++) hw[r * 256] = f2bf(fmaxf(a[r], 0.f));
            }
            __syncthreads();   // hid(m3) ready

            // E) W2-m3 accumulate + leaky + store
#pragma unroll 1
            for (int h0 = 0; h0 < 256; h0 += 8) {
                float wA[8], wB[8];
#pragma unroll
                for (int j = 0; j < 8; j++) {
                    const int wb = (h0 + j) * 512;
                    wA[j] = wld<F32>(wp.p[10], wb + colA);
                    wB[j] = wld<F32>(wp.p[10], wb + colB);
                }
#pragma unroll
                for (int r = 0; r < 32; r++) {
                    float x8[8];
                    ld8bf(hidb + r * 256 + h0, x8);
#pragma unroll
                    for (int j = 0; j < 8; j++) {
                        accA[r] = fmaf(x8[j], wA[j], accA[r]);
                        accB[r] = fmaf(x8[j], wB[j], accB[r]);
                    }
                }
            }
#pragma unroll
            for (int r = 0; r < 32; r++) {
                const int rg = row0 + rh + r;
                if (rg < NP) {
                    float vA = accA[r]; vA = vA > 0.f ? vA : 0.01f * vA;
                    float vB = accB[r]; vB = vB > 0.f ? vB : 0.01f * vB;
                    if constexpr (F32) {
                        ((float*)outp)[(size_t)rg * 512 + colA] = vA;
                        ((float*)outp)[(size_t)rg * 512 + colB] = vB;
                    } else {
                        ((u16*)outp)[(size_t)rg * 512 + colA] = f2bf(vA);
                        ((u16*)outp)[(size_t)rg * 512 + colB] = f2bf(vB);
                    }
                }
            }
            __syncthreads();   // protect hidb/ftbv for next row-half
        }
    }
}

__global__ __launch_bounds__(256)
__attribute__((amdgpu_waves_per_eu(2, 2)))
void k_mega(
    const void* __restrict__ coords, const void* __restrict__ feats,
    const int* __restrict__ nidx, WPtrs wp, void* __restrict__ outp)
{
    __shared__ __align__(16) u16 xt[64 * XS];
    __shared__ __align__(16) u16 pt[64 * XS];
    __shared__ __align__(16) u16 hsb[64 * HSTR];
    __shared__ __align__(16) float red[256];   // cross-wave softmax reduce (1KB)
    __shared__ int sflag;

    // per-block dtype detection: bf16-interpret the first 128 u16 of coords.
    if (threadIdx.x == 0) {
        const u16* c16 = (const u16*)coords;
        int bad = 0;
        for (int i = 0; i < 128; i++) {
            u32 e = (c16[i] >> 7) & 0xFFu;
            bad += (e != 0u && (e < 63u || e > 191u)) ? 1 : 0;
        }
        sflag = bad;
    }
    __syncthreads();

    if (sflag) run_all<true >(coords, feats, nidx, wp, outp, xt, pt, hsb, red);
    else       run_all<false>(coords, feats, nidx, wp, outp, xt, pt, hsb, red);
}

// ---------------- host ----------------
extern "C" void kernel_launch(void* const* d_in, const int* in_sizes, int n_in,
                              void* d_out, int out_size, void* d_ws, size_t ws_size,
                              hipStream_t stream)
{
    const void* coords = d_in[0];
    const void* feats  = d_in[1];
    const int*  nidx   = (const int*)d_in[2];

    WPtrs wp;
    for (int i = 0; i < 28; i++) wp.p[i] = d_in[3 + i];
    // p[0..3]=m1, p[4..7]=m2, p[8..11]=m3, p[12..15]=l1, p[16..19]=l2, p[20..23]=p1, p[24..27]=p2

    k_mega<<<(NP + 63) / 64, 256, 0, stream>>>(coords, feats, nidx, wp, d_out);
}

// Round 5
// 5592.057 us; speedup vs baseline: 2.8292x; 1.7325x over previous
//
#include <hip/hip_runtime.h>
#include <stdint.h>

#define NP 100000

typedef unsigned short u16;
typedef unsigned int   u32;

// intra-wave LDS RAW fence: drains ds_writes before subsequent ds_reads issue
#define LFENCE() asm volatile("s_waitcnt lgkmcnt(0)" ::: "memory")

__device__ __forceinline__ float bf2f(u16 v) { return __uint_as_float(((u32)v) << 16); }
__device__ __forceinline__ u16 f2bf(float f) {
    u32 x = __float_as_uint(f);
    u32 r = x + 0x7fffu + ((x >> 16) & 1u);
    return (u16)(r >> 16);
}
__device__ __forceinline__ void ld8bf(const u16* p, float* x) {
    uint4 u = *reinterpret_cast<const uint4*>(p);
    x[0] = __uint_as_float(u.x << 16); x[1] = __uint_as_float(u.x & 0xffff0000u);
    x[2] = __uint_as_float(u.y << 16); x[3] = __uint_as_float(u.y & 0xffff0000u);
    x[4] = __uint_as_float(u.z << 16); x[5] = __uint_as_float(u.z & 0xffff0000u);
    x[6] = __uint_as_float(u.w << 16); x[7] = __uint_as_float(u.w & 0xffff0000u);
}

// dtype-dual scalar weight load (per-lane address -> coalesced vector VMEM)
template<bool F32>
__device__ __forceinline__ float wld(const void* W, int idx) {
    if constexpr (F32) return ((const float*)W)[idx];
    else return bf2f(((const u16*)W)[idx]);
}
// dtype-dual 8-wide activation load (LDS or any address space)
template<bool F32>
__device__ __forceinline__ void ldx8(const void* p, int i, float* x) {
    if constexpr (F32) {
        const float* q = (const float*)p + i;
        float4 a = *reinterpret_cast<const float4*>(q);
        float4 b = *reinterpret_cast<const float4*>(q + 4);
        x[0]=a.x; x[1]=a.y; x[2]=a.z; x[3]=a.w;
        x[4]=b.x; x[5]=b.y; x[6]=b.z; x[7]=b.w;
    } else {
        ld8bf((const u16*)p + i, x);
    }
}

// ---------------- col-per-lane linear+relu -> LDS bf16 ----------------
// Computes relu(in[rbIn..rbIn+RW) x W1 + b1) for ALL H columns, written to
// outb rows [rbOut..rbOut+RW) with stride H. Columns processed in pairs of
// 64 (cA = c+lane, cB = c+64+lane). Weights: per-lane coalesced VMEM.
// Activations: wave-uniform LDS (or staged-native) broadcast reads.
template<bool WF32, bool INF32, int RW, int CIN, int H>
__device__ __forceinline__ void lin_relu(const void* __restrict__ inb, int SIN,
                                         const void* __restrict__ W1, const void* __restrict__ b1,
                                         u16* __restrict__ outb, int rbIn, int rbOut, int lane)
{
#pragma unroll 1
    for (int c = 0; c < H; c += 128) {
        const int cA = c + lane, cB = c + 64 + lane;
        float aA[RW], aB[RW];
        {
            const float bbA = wld<WF32>(b1, cA), bbB = wld<WF32>(b1, cB);
#pragma unroll
            for (int r = 0; r < RW; r++) { aA[r] = bbA; aB[r] = bbB; }
        }
#pragma unroll 1
        for (int i0 = 0; i0 < CIN; i0 += 8) {
            float wA[8], wB[8];
#pragma unroll
            for (int j = 0; j < 8; j++) {
                wA[j] = wld<WF32>(W1, (i0 + j) * H + cA);
                wB[j] = wld<WF32>(W1, (i0 + j) * H + cB);
            }
#pragma unroll 8
            for (int r = 0; r < RW; r++) {
                float x8[8];
                ldx8<INF32>(inb, (rbIn + r) * SIN + i0, x8);
#pragma unroll
                for (int j = 0; j < 8; j++) {
                    aA[r] = fmaf(x8[j], wA[j], aA[r]);
                    aB[r] = fmaf(x8[j], wB[j], aB[r]);
                }
            }
        }
#pragma unroll
        for (int r = 0; r < RW; r++) {
            outb[(rbOut + r) * H + cA] = f2bf(fmaxf(aA[r], 0.f));
            outb[(rbOut + r) * H + cB] = f2bf(fmaxf(aB[r], 0.f));
        }
    }
}

// ---------------- col-per-lane second-layer accumulate ----------------
// acc{A,B}[RW] += hid[rb0..rb0+RW) x W2[:, cA/cB]; hid bf16 LDS stride HID.
template<bool WF32, int RW, int HID>
__device__ __forceinline__ void lin_acc2(const u16* __restrict__ hidb, int rb0,
                                         const void* __restrict__ W2, int CO, int cA, int cB,
                                         float* __restrict__ accA, float* __restrict__ accB)
{
#pragma unroll 1
    for (int i0 = 0; i0 < HID; i0 += 8) {
        float wA[8], wB[8];
#pragma unroll
        for (int j = 0; j < 8; j++) {
            wA[j] = wld<WF32>(W2, (i0 + j) * CO + cA);
            wB[j] = wld<WF32>(W2, (i0 + j) * CO + cB);
        }
#pragma unroll 8
        for (int r = 0; r < RW; r++) {
            float x8[8];
            ld8bf(hidb + (rb0 + r) * HID + i0, x8);
#pragma unroll
            for (int j = 0; j < 8; j++) {
                accA[r] = fmaf(x8[j], wA[j], accA[r]);
                accB[r] = fmaf(x8[j], wB[j], accB[r]);
            }
        }
    }
}

// ---------------- LSE stage: geometry encoder + channel-softmax pool --------
// Barrier-free: wave waveU owns point pp = g*4+waveU each pass; its 16 LDS
// hid rows (hidw, wave-private) are exactly that point's 16 neighbors, so the
// k-reduction is register-local. Weights per-lane VMEM; geometry broadcast
// via shfl (each 16-lane group computed all 16 neighbors' 10-vectors).
template<bool F32>
__device__ __forceinline__ void stage_phase(
    const void* __restrict__ coords, const int* __restrict__ nidx,
    const void* __restrict__ lW1, const void* __restrict__ lb1,
    const void* __restrict__ lW2, const void* __restrict__ lb2,
    int row0, int waveU, int lane,
    const u16* __restrict__ xt, u16* __restrict__ pt,
    u16* __restrict__ hidw)
{
    const int k = lane & 15;
    const int sbase = lane & 48;
    float w1r[10];
#pragma unroll
    for (int i = 0; i < 10; i++) w1r[i] = wld<F32>(lW1, i * 64 + lane);
    const float b1r = wld<F32>(lb1, lane);
    const float b2A = wld<F32>(lb2, lane), b2B = wld<F32>(lb2, 64 + lane);

#pragma unroll 1
    for (int g = 0; g < 16; g++) {
        const int pp = g * 4 + waveU;
        int n = row0 + pp; if (n >= NP) n = NP - 1;

        // geometry for neighbor k (each 16-lane group computes all 16 k's)
        float v[10];
        {
            const int j = nidx[(size_t)n * 16 + k];
            float ox, oy, oz, nbx, nby, nbz;
            if constexpr (F32) {
                const float* cf = (const float*)coords;
                ox = cf[n*3+0]; oy = cf[n*3+1]; oz = cf[n*3+2];
                nbx = cf[j*3+0]; nby = cf[j*3+1]; nbz = cf[j*3+2];
            } else {
                const u16* cb = (const u16*)coords;
                ox = bf2f(cb[n*3+0]); oy = bf2f(cb[n*3+1]); oz = bf2f(cb[n*3+2]);
                nbx = bf2f(cb[j*3+0]); nby = bf2f(cb[j*3+1]); nbz = bf2f(cb[j*3+2]);
            }
            float rx = ox-nbx, ry = oy-nby, rz = oz-nbz;
            float dd = sqrtf(rx*rx + ry*ry + rz*rz);
            v[0]=ox; v[1]=oy; v[2]=oz; v[3]=nbx; v[4]=nby; v[5]=nbz;
            v[6]=rx; v[7]=ry; v[8]=rz; v[9]=dd;
        }

        // feature-half stats for my point (shift-free softmax)
        const float xa = bf2f(xt[pp * 128 + lane]);
        const float xb = bf2f(xt[pp * 128 + 64 + lane]);
        const float exa = __expf(xa), exb = __expf(xb);
        float Fh = exa + exb;
#pragma unroll
        for (int m = 1; m < 64; m <<= 1) Fh += __shfl_xor(Fh, m, 64);

        // L1: 10 -> 64 for my point's 16 neighbors (row r = neighbor r), col=lane
#pragma unroll 4
        for (int r = 0; r < 16; r++) {
            float a = b1r;
#pragma unroll
            for (int i = 0; i < 10; i++)
                a = fmaf(__shfl(v[i], sbase | r, 64), w1r[i], a);
            hidw[r * 64 + lane] = f2bf(fmaxf(a, 0.f));
        }
        LFENCE();   // intra-wave RAW: hid writes drained before reads

        // L2: 64 -> 128, rows register-resident per thread
        float eA[16], eB[16];
#pragma unroll
        for (int r = 0; r < 16; r++) { eA[r] = b2A; eB[r] = b2B; }
#pragma unroll 1
        for (int i0 = 0; i0 < 64; i0 += 8) {
            float wA[8], wB[8];
#pragma unroll
            for (int jj = 0; jj < 8; jj++) {
                wA[jj] = wld<F32>(lW2, (i0 + jj) * 128 + lane);
                wB[jj] = wld<F32>(lW2, (i0 + jj) * 128 + 64 + lane);
            }
#pragma unroll 8
            for (int r = 0; r < 16; r++) {
                float x8[8];
                ld8bf(hidw + r * 64 + i0, x8);
#pragma unroll
                for (int jj = 0; jj < 8; jj++) {
                    eA[r] = fmaf(x8[jj], wA[jj], eA[r]);
                    eB[r] = fmaf(x8[jj], wB[jj], eB[r]);
                }
            }
        }

        // channel-softmax + pool over the 16 neighbors (k-sum register-local)
        float T = 0.f, pA = 0.f, pB = 0.f;
#pragma unroll
        for (int r = 0; r < 16; r++) {
            const float qa = __expf(eA[r]), qb = __expf(eB[r]);
            float s = qa + qb;
#pragma unroll
            for (int m = 1; m < 64; m <<= 1) s += __shfl_xor(s, m, 64);
            const float invd = 1.0f / (s + Fh);
            T += invd;
            pA = fmaf(qa * eA[r], invd, pA);
            pB = fmaf(qb * eB[r], invd, pB);
        }
        u16* prow = pt + pp * 256;
        prow[lane]       = f2bf(pA);
        prow[64 + lane]  = f2bf(pB);
        prow[128 + lane] = f2bf(xa * exa * T);
        prow[192 + lane] = f2bf(xb * exb * T);
        // WAR on hidw next pass is safe: L2's reads were data-consumed above.
    }
}

// ---------------- the fused per-point network ----------------
struct WPtrs { const void* p[28]; };

template<bool F32>
__device__ __forceinline__ void run_all(
    const void* __restrict__ coords, const void* __restrict__ feats,
    const int* __restrict__ nidx, const WPtrs& wp, void* __restrict__ outp,
    u16* __restrict__ xt, u16* __restrict__ pt, u16* __restrict__ hidb)
{
    const int waveU = __builtin_amdgcn_readfirstlane((int)(threadIdx.x >> 6));
    const int lane  = threadIdx.x & 63;
    const int row0  = blockIdx.x * 64;
    const int rb    = waveU * 16;              // this wave's 16 rows
    u16* hidw = hidb + waveU * 2048;           // wave-private hid region (4 KB)

    // ---- phase 1: m1 (128 -> 128 -> 128), feats -> xt. Barrier-free. ----
    {
        // stage this wave's 16 feats rows into pt (native dtype)
        {
            const int r = rb + (lane >> 2), cc = (lane & 3) * 32;
            int rg = row0 + r; if (rg >= NP) rg = NP - 1;
            if constexpr (F32) {
                const float* src = (const float*)feats + (size_t)rg * 128 + cc;
                float* dst = (float*)pt + r * 128 + cc;
#pragma unroll
                for (int q = 0; q < 32; q += 4)
                    *reinterpret_cast<float4*>(dst + q) = *reinterpret_cast<const float4*>(src + q);
            } else {
                const u16* src = (const u16*)feats + (size_t)rg * 128 + cc;
                u16* dst = pt + r * 128 + cc;
#pragma unroll
                for (int q = 0; q < 32; q += 8)
                    *reinterpret_cast<uint4*>(dst + q) = *reinterpret_cast<const uint4*>(src + q);
            }
        }
        LFENCE();
        lin_relu<F32, F32, 16, 128, 128>((const void*)pt, 128, wp.p[0], wp.p[1], hidw, rb, 0, lane);
        LFENCE();
        float accA[16], accB[16];
        {
            const float bA = wld<F32>(wp.p[3], lane), bB = wld<F32>(wp.p[3], 64 + lane);
#pragma unroll
            for (int r = 0; r < 16; r++) { accA[r] = bA; accB[r] = bB; }
        }
        lin_acc2<F32, 16, 128>(hidw, 0, wp.p[2], 128, lane, 64 + lane, accA, accB);
#pragma unroll
        for (int r = 0; r < 16; r++) {
            xt[(rb + r) * 128 + lane]      = f2bf(accA[r]);
            xt[(rb + r) * 128 + 64 + lane] = f2bf(accB[r]);
        }
    }
    __syncthreads();

    // ---- phase 2: lse1 + pool -> pt[64][256]. Barrier-free. ----
    stage_phase<F32>(coords, nidx, wp.p[12], wp.p[13], wp.p[14], wp.p[15],
                     row0, waveU, lane, xt, pt, hidw);
    __syncthreads();

    // ---- phase 3: p1 (256 -> 256 -> 128), pt -> xt. Barrier-free. ----
#pragma unroll 1
    for (int sh = 0; sh < 16; sh += 8) {
        lin_relu<F32, false, 8, 256, 256>((const void*)pt, 256, wp.p[20], wp.p[21], hidw, rb + sh, 0, lane);
        LFENCE();
        float accA[8], accB[8];
        {
            const float bA = wld<F32>(wp.p[23], lane), bB = wld<F32>(wp.p[23], 64 + lane);
#pragma unroll
            for (int r = 0; r < 8; r++) { accA[r] = bA; accB[r] = bB; }
        }
        lin_acc2<F32, 8, 256>(hidw, 0, wp.p[22], 128, lane, 64 + lane, accA, accB);
#pragma unroll
        for (int r = 0; r < 8; r++) {
            xt[(rb + sh + r) * 128 + lane]      = f2bf(accA[r]);
            xt[(rb + sh + r) * 128 + 64 + lane] = f2bf(accB[r]);
        }
    }
    __syncthreads();

    // ---- phase 4: lse2 -> pt. ----
    stage_phase<F32>(coords, nidx, wp.p[16], wp.p[17], wp.p[18], wp.p[19],
                     row0, waveU, lane, xt, pt, hidw);
    __syncthreads();

    // ---- phase 5: p2 (256 -> 256 -> 256), pt -> pt in place. Barrier-free. ----
#pragma unroll 1
    for (int sh = 0; sh < 16; sh += 8) {
        lin_relu<F32, false, 8, 256, 256>((const void*)pt, 256, wp.p[24], wp.p[25], hidw, rb + sh, 0, lane);
        LFENCE();
#pragma unroll 1
        for (int cp = 0; cp < 256; cp += 128) {
            float accA[8], accB[8];
            {
                const float bA = wld<F32>(wp.p[27], cp + lane), bB = wld<F32>(wp.p[27], cp + 64 + lane);
#pragma unroll
                for (int r = 0; r < 8; r++) { accA[r] = bA; accB[r] = bB; }
            }
            lin_acc2<F32, 8, 256>(hidw, 0, wp.p[26], 256, cp + lane, cp + 64 + lane, accA, accB);
#pragma unroll
            for (int r = 0; r < 8; r++) {
                pt[(rb + sh + r) * 256 + cp + lane]      = f2bf(accA[r]);
                pt[(rb + sh + r) * 256 + cp + 64 + lane] = f2bf(accB[r]);
            }
        }
    }
    __syncthreads();

    // ---- phase 6: leaky(m2(pt) + m3(feats)) -> out ----
    // m2-L1 row-split into hidb[32][384]; L2 col-split (16-row chunks, acc[16]x2).
    // m3 staged per 16-row chunk: ftb (native) in xt[0:4096], hid in xt[4096:8192].
    const int colA = waveU * 128 + lane, colB = colA + 64;
    const float bA6 = wld<F32>(wp.p[7], colA) + wld<F32>(wp.p[11], colA);
    const float bB6 = wld<F32>(wp.p[7], colB) + wld<F32>(wp.p[11], colB);
#pragma unroll 1
    for (int rh = 0; rh < 64; rh += 32) {
        lin_relu<F32, false, 8, 256, 384>((const void*)pt, 256, wp.p[4], wp.p[5],
                                          hidb, rh + waveU * 8, waveU * 8, lane);
        __syncthreads();   // hidb[32][384] complete (cross-wave for col-split L2)
#pragma unroll 1
        for (int q = 0; q < 32; q += 16) {
            // stage feats rows rh+q..+16 -> xt[0:4096] native (wave-private rows)
            {
                const int rl = waveU * 4 + (lane >> 4);
                const int cc = (lane & 15) * 8;
                int rg = row0 + rh + q + rl; if (rg >= NP) rg = NP - 1;
                if constexpr (F32) {
                    const float* src = (const float*)feats + (size_t)rg * 128 + cc;
                    float* dst = (float*)xt + rl * 128 + cc;
#pragma unroll
                    for (int u = 0; u < 8; u += 4)
                        *reinterpret_cast<float4*>(dst + u) = *reinterpret_cast<const float4*>(src + u);
                } else {
                    const u16* src = (const u16*)feats + (size_t)rg * 128 + cc;
                    u16* dst = xt + rl * 128 + cc;
                    *reinterpret_cast<uint4*>(dst) = *reinterpret_cast<const uint4*>(src);
                }
            }
            LFENCE();
            // m3-L1: 128 -> 256 for this wave's 4 rows -> xt[4096:8192] ([16][256])
            lin_relu<F32, F32, 4, 128, 256>((const void*)xt, 128, wp.p[8], wp.p[9],
                                            xt + 4096, waveU * 4, waveU * 4, lane);
            __syncthreads();   // m3 hid complete (cross-wave)
            float accA[16], accB[16];
#pragma unroll
            for (int r = 0; r < 16; r++) { accA[r] = bA6; accB[r] = bB6; }
            lin_acc2<F32, 16, 384>(hidb, q, wp.p[6], 512, colA, colB, accA, accB);
            lin_acc2<F32, 16, 256>(xt + 4096, 0, wp.p[10], 512, colA, colB, accA, accB);
#pragma unroll
            for (int r = 0; r < 16; r++) {
                const int rg = row0 + rh + q + r;
                if (rg < NP) {
                    float vA = accA[r]; vA = vA > 0.f ? vA : 0.01f * vA;
                    float vB = accB[r]; vB = vB > 0.f ? vB : 0.01f * vB;
                    if constexpr (F32) {
                        ((float*)outp)[(size_t)rg * 512 + colA] = vA;
                        ((float*)outp)[(size_t)rg * 512 + colB] = vB;
                    } else {
                        ((u16*)outp)[(size_t)rg * 512 + colA] = f2bf(vA);
                        ((u16*)outp)[(size_t)rg * 512 + colB] = f2bf(vB);
                    }
                }
            }
            __syncthreads();   // protect xt (ftb/m3 hid) before next chunk/half
        }
    }
}

__global__ __launch_bounds__(256, 2) void k_mega(
    const void* __restrict__ coords, const void* __restrict__ feats,
    const int* __restrict__ nidx, WPtrs wp, void* __restrict__ outp)
{
    __shared__ __align__(16) u16 xt[64 * 128];     // 16 KB: per-point 128-ch state
    __shared__ __align__(16) u16 pt[64 * 256];     // 32 KB: per-point 256-ch state / feats stage
    __shared__ __align__(16) u16 hidb[12288];      // 24 KB: hidden stage (4x2048 wave-private or global)
    __shared__ int sflag;

    // per-block dtype detection: bf16-interpret the first 128 u16 of coords.
    if (threadIdx.x == 0) {
        const u16* c16 = (const u16*)coords;
        int bad = 0;
        for (int i = 0; i < 128; i++) {
            u32 e = (c16[i] >> 7) & 0xFFu;
            bad += (e != 0u && (e < 63u || e > 191u)) ? 1 : 0;
        }
        sflag = bad;
    }
    __syncthreads();

    if (sflag) run_all<true >(coords, feats, nidx, wp, outp, xt, pt, hidb);
    else       run_all<false>(coords, feats, nidx, wp, outp, xt, pt, hidb);
}

// ---------------- host ----------------
extern "C" void kernel_launch(void* const* d_in, const int* in_sizes, int n_in,
                              void* d_out, int out_size, void* d_ws, size_t ws_size,
                              hipStream_t stream)
{
    const void* coords = d_in[0];
    const void* feats  = d_in[1];
    const int*  nidx   = (const int*)d_in[2];

    WPtrs wp;
    for (int i = 0; i < 28; i++) wp.p[i] = d_in[3 + i];
    // p[0..3]=m1, p[4..7]=m2, p[8..11]=m3, p[12..15]=l1, p[16..19]=l2, p[20..23]=p1, p[24..27]=p2

    k_mega<<<(NP + 63) / 64, 256, 0, stream>>>(coords, feats, nidx, wp, d_out);
}

// Round 6
// 2193.777 us; speedup vs baseline: 7.2117x; 2.5491x over previous
//
#include <hip/hip_runtime.h>
#include <stdint.h>

#define NP 100000

typedef unsigned short u16;
typedef unsigned int   u32;

typedef __attribute__((ext_vector_type(8))) short bf16x8;
typedef __attribute__((ext_vector_type(4))) float f32x4;

// intra-wave LDS RAW fence: drains ds_writes before subsequent ds_reads issue
#define LFENCE() asm volatile("s_waitcnt lgkmcnt(0)" ::: "memory")

__device__ __forceinline__ float bf2f(u16 v) { return __uint_as_float(((u32)v) << 16); }
__device__ __forceinline__ u16 f2bf(float f) {
    u32 x = __float_as_uint(f);
    u32 r = x + 0x7fffu + ((x >> 16) & 1u);
    return (u16)(r >> 16);
}
__device__ __forceinline__ u32 packbf2(float a, float b) {
    return (u32)f2bf(a) | ((u32)f2bf(b) << 16);
}
__device__ __forceinline__ void ld8bf(const u16* p, float* x) {
    uint4 u = *reinterpret_cast<const uint4*>(p);
    x[0] = __uint_as_float(u.x << 16); x[1] = __uint_as_float(u.x & 0xffff0000u);
    x[2] = __uint_as_float(u.y << 16); x[3] = __uint_as_float(u.y & 0xffff0000u);
    x[4] = __uint_as_float(u.z << 16); x[5] = __uint_as_float(u.z & 0xffff0000u);
    x[6] = __uint_as_float(u.w << 16); x[7] = __uint_as_float(u.w & 0xffff0000u);
}

template<bool F32>
__device__ __forceinline__ float wld(const void* W, int idx) {
    if constexpr (F32) return ((const float*)W)[idx];
    else return bf2f(((const u16*)W)[idx]);
}
template<bool F32>
__device__ __forceinline__ void ldx8(const void* p, int i, float* x) {
    if constexpr (F32) {
        const float* q = (const float*)p + i;
        float4 a = *reinterpret_cast<const float4*>(q);
        float4 b = *reinterpret_cast<const float4*>(q + 4);
        x[0]=a.x; x[1]=a.y; x[2]=a.z; x[3]=a.w;
        x[4]=b.x; x[5]=b.y; x[6]=b.z; x[7]=b.w;
    } else {
        ld8bf((const u16*)p + i, x);
    }
}

struct WPtrs { const void* p[28]; };

// ================== LSE stage (round-5, strides templated) ==================
// Barrier-free: wave waveU owns point pp = g*4+waveU each pass; its 16 LDS hid
// rows (hidw, wave-private) are that point's 16 neighbors -> k-reduction is
// register-local. Weights per-lane VMEM; geometry broadcast via shfl.
template<bool F32, int SXT, int SPT>
__device__ __forceinline__ void stage_phase(
    const void* __restrict__ coords, const int* __restrict__ nidx,
    const void* __restrict__ lW1, const void* __restrict__ lb1,
    const void* __restrict__ lW2, const void* __restrict__ lb2,
    int row0, int waveU, int lane,
    const u16* __restrict__ xt, u16* __restrict__ pt,
    u16* __restrict__ hidw)
{
    const int k = lane & 15;
    const int sbase = lane & 48;
    float w1r[10];
#pragma unroll
    for (int i = 0; i < 10; i++) w1r[i] = wld<F32>(lW1, i * 64 + lane);
    const float b1r = wld<F32>(lb1, lane);
    const float b2A = wld<F32>(lb2, lane), b2B = wld<F32>(lb2, 64 + lane);

#pragma unroll 1
    for (int g = 0; g < 16; g++) {
        const int pp = g * 4 + waveU;
        int n = row0 + pp; if (n >= NP) n = NP - 1;

        float v[10];
        {
            const int j = nidx[(size_t)n * 16 + k];
            float ox, oy, oz, nbx, nby, nbz;
            if constexpr (F32) {
                const float* cf = (const float*)coords;
                ox = cf[n*3+0]; oy = cf[n*3+1]; oz = cf[n*3+2];
                nbx = cf[j*3+0]; nby = cf[j*3+1]; nbz = cf[j*3+2];
            } else {
                const u16* cb = (const u16*)coords;
                ox = bf2f(cb[n*3+0]); oy = bf2f(cb[n*3+1]); oz = bf2f(cb[n*3+2]);
                nbx = bf2f(cb[j*3+0]); nby = bf2f(cb[j*3+1]); nbz = bf2f(cb[j*3+2]);
            }
            float rx = ox-nbx, ry = oy-nby, rz = oz-nbz;
            float dd = sqrtf(rx*rx + ry*ry + rz*rz);
            v[0]=ox; v[1]=oy; v[2]=oz; v[3]=nbx; v[4]=nby; v[5]=nbz;
            v[6]=rx; v[7]=ry; v[8]=rz; v[9]=dd;
        }

        const float xa = bf2f(xt[pp * SXT + lane]);
        const float xb = bf2f(xt[pp * SXT + 64 + lane]);
        const float exa = __expf(xa), exb = __expf(xb);
        float Fh = exa + exb;
#pragma unroll
        for (int m = 1; m < 64; m <<= 1) Fh += __shfl_xor(Fh, m, 64);

#pragma unroll 4
        for (int r = 0; r < 16; r++) {
            float a = b1r;
#pragma unroll
            for (int i = 0; i < 10; i++)
                a = fmaf(__shfl(v[i], sbase | r, 64), w1r[i], a);
            hidw[r * 64 + lane] = f2bf(fmaxf(a, 0.f));
        }
        LFENCE();

        float eA[16], eB[16];
#pragma unroll
        for (int r = 0; r < 16; r++) { eA[r] = b2A; eB[r] = b2B; }
#pragma unroll 1
        for (int i0 = 0; i0 < 64; i0 += 8) {
            float wA[8], wB[8];
#pragma unroll
            for (int jj = 0; jj < 8; jj++) {
                wA[jj] = wld<F32>(lW2, (i0 + jj) * 128 + lane);
                wB[jj] = wld<F32>(lW2, (i0 + jj) * 128 + 64 + lane);
            }
#pragma unroll 8
            for (int r = 0; r < 16; r++) {
                float x8[8];
                ld8bf(hidw + r * 64 + i0, x8);
#pragma unroll
                for (int jj = 0; jj < 8; jj++) {
                    eA[r] = fmaf(x8[jj], wA[jj], eA[r]);
                    eB[r] = fmaf(x8[jj], wB[jj], eB[r]);
                }
            }
        }

        float T = 0.f, pA = 0.f, pB = 0.f;
#pragma unroll
        for (int r = 0; r < 16; r++) {
            const float qa = __expf(eA[r]), qb = __expf(eB[r]);
            float s = qa + qb;
#pragma unroll
            for (int m = 1; m < 64; m <<= 1) s += __shfl_xor(s, m, 64);
            const float invd = 1.0f / (s + Fh);
            T += invd;
            pA = fmaf(qa * eA[r], invd, pA);
            pB = fmaf(qb * eB[r], invd, pB);
        }
        u16* prow = pt + pp * SPT;
        prow[lane]       = f2bf(pA);
        prow[64 + lane]  = f2bf(pB);
        prow[128 + lane] = f2bf(xa * exa * T);
        prow[192 + lane] = f2bf(xb * exb * T);
    }
}

// =================== MFMA primitives (16x16x32 bf16) ===================
// B-frags prepacked in ws: frag(n,ks,lane,e) = W[ks*32+(lane>>4)*8+e][n*16+(lane&15)]
// at u16 offset ((n*K32+ks)*64+lane)*8. A-frag: row=lane&15, k=8*(lane>>4)+e.
// D: col=lane&15, row=4*(lane>>4)+r  [m89-verified].

// Y[rbY..rbY+RN)[H] = act(X[rbX..)[CIN] @ Wp + b1); waves split H (NT tiles each).
template<bool WF32, bool RELU, int RN, int CIN, int H, int SX, int SY>
__device__ __forceinline__ void mfma_lin(const u16* __restrict__ X, int rbX,
                                         const u16* __restrict__ Wp, const void* __restrict__ b1,
                                         u16* __restrict__ Y, int rbY, int waveU, int lane)
{
    constexpr int NT  = H / 64;    // n-tiles per wave
    constexpr int MT  = RN / 16;
    constexpr int K32 = CIN / 32;
    const int l15 = lane & 15, lhi = lane >> 4;
#pragma unroll 1
    for (int n = 0; n < NT; n++) {
        const int nt = waveU * NT + n;
        const int ncol = nt * 16 + l15;
        const float bb = wld<WF32>(b1, ncol);
        f32x4 acc[MT];
#pragma unroll
        for (int m = 0; m < MT; m++) acc[m] = f32x4{bb, bb, bb, bb};
#pragma unroll
        for (int ks = 0; ks < K32; ks++) {
            bf16x8 b = *reinterpret_cast<const bf16x8*>(Wp + ((size_t)(nt * K32 + ks) * 64 + lane) * 8);
#pragma unroll
            for (int m = 0; m < MT; m++) {
                bf16x8 a = *reinterpret_cast<const bf16x8*>(X + (rbX + m * 16 + l15) * SX + ks * 32 + lhi * 8);
                acc[m] = __builtin_amdgcn_mfma_f32_16x16x32_bf16(a, b, acc[m], 0, 0, 0);
            }
        }
#pragma unroll
        for (int m = 0; m < MT; m++) {
#pragma unroll
            for (int r = 0; r < 4; r++) {
                float v = acc[m][r];
                if constexpr (RELU) v = fmaxf(v, 0.f);
                Y[(rbY + m * 16 + lhi * 4 + r) * SY + ncol] = f2bf(v);
            }
        }
    }
}

// acc[n*MT+m] += Xh[0..MT*16)[HID] @ Wp (wave's CO/4 column chunk)
template<int HID, int CO, int SH, int MT>
__device__ __forceinline__ void mfma_acc(const u16* __restrict__ Xh,
                                         const u16* __restrict__ Wp,
                                         f32x4* __restrict__ acc, int waveU, int lane)
{
    constexpr int NTL = CO / 64;
    constexpr int K32 = HID / 32;
    const int l15 = lane & 15, lhi = lane >> 4;
#pragma unroll 1
    for (int n = 0; n < NTL; n++) {
        const int nt = waveU * NTL + n;
#pragma unroll
        for (int ks = 0; ks < K32; ks++) {
            bf16x8 b = *reinterpret_cast<const bf16x8*>(Wp + ((size_t)(nt * K32 + ks) * 64 + lane) * 8);
#pragma unroll
            for (int m = 0; m < MT; m++) {
                bf16x8 a = *reinterpret_cast<const bf16x8*>(Xh + (m * 16 + l15) * SH + ks * 32 + lhi * 8);
                acc[n * MT + m] = __builtin_amdgcn_mfma_f32_16x16x32_bf16(a, b, acc[n * MT + m], 0, 0, 0);
            }
        }
    }
}

// ================= MFMA main kernel =================
// LDS strides padded +8 u16 (136/264/392 == 4 dw mod 32 -> 2-way-free A-frag reads)
template<bool F32>
__device__ __forceinline__ void run_all_mx(
    const void* __restrict__ coords, const void* __restrict__ feats,
    const int* __restrict__ nidx, const WPtrs& wp,
    const u16* __restrict__ ws, void* __restrict__ outp,
    u16* __restrict__ XT, u16* __restrict__ PT, u16* __restrict__ HB)
{
    const int waveU = __builtin_amdgcn_readfirstlane((int)(threadIdx.x >> 6));
    const int lane  = threadIdx.x & 63;
    const int row0  = blockIdx.x * 64;
    const int l15 = lane & 15, lhi = lane >> 4;

    // packed-weight bases (u16 offsets; see host)
    const u16* Wm1a = ws;           const u16* Wm1b = ws + 16384;
    const u16* Wm2a = ws + 32768;   const u16* Wm2b = ws + 131072;
    const u16* Wm3a = ws + 327680;  const u16* Wm3b = ws + 360448;
    const u16* Wp1a = ws + 491520;  const u16* Wp1b = ws + 557056;
    const u16* Wp2a = ws + 589824;  const u16* Wp2b = ws + 655360;

    // ---- phase 1: m1 (feats -> xt). Stage feats[64][136] bf16 into HB. ----
    {
        const int t = (int)threadIdx.x;
        const int r = t >> 2, c0 = (t & 3) * 32;
        int rg = row0 + r; if (rg >= NP) rg = NP - 1;
        if constexpr (F32) {
            const float* src = (const float*)feats + (size_t)rg * 128 + c0;
            u32* dst = (u32*)(HB + r * 136 + c0);
#pragma unroll
            for (int q = 0; q < 32; q += 8) {
                float4 a = *reinterpret_cast<const float4*>(src + q);
                float4 b = *reinterpret_cast<const float4*>(src + q + 4);
                dst[(q >> 1) + 0] = packbf2(a.x, a.y); dst[(q >> 1) + 1] = packbf2(a.z, a.w);
                dst[(q >> 1) + 2] = packbf2(b.x, b.y); dst[(q >> 1) + 3] = packbf2(b.z, b.w);
            }
        } else {
            const u16* src = (const u16*)feats + (size_t)rg * 128 + c0;
            u16* dst = HB + r * 136 + c0;
#pragma unroll
            for (int q = 0; q < 32; q += 8)
                *reinterpret_cast<uint4*>(dst + q) = *reinterpret_cast<const uint4*>(src + q);
        }
    }
    __syncthreads();
    mfma_lin<F32, true,  64, 128, 128, 136, 136>(HB, 0, Wm1a, wp.p[1], PT, 0, waveU, lane);
    __syncthreads();
    mfma_lin<F32, false, 64, 128, 128, 136, 136>(PT, 0, Wm1b, wp.p[3], XT, 0, waveU, lane);
    __syncthreads();

    // ---- phase 2: lse1 -> PT ----
    stage_phase<F32, 136, 264>(coords, nidx, wp.p[12], wp.p[13], wp.p[14], wp.p[15],
                               row0, waveU, lane, XT, PT, HB + waveU * 1024);
    __syncthreads();

    // ---- phase 3: p1 (PT -> XT), halves of 32 rows ----
#pragma unroll 1
    for (int rh = 0; rh < 64; rh += 32) {
        mfma_lin<F32, true,  32, 256, 256, 264, 264>(PT, rh, Wp1a, wp.p[21], HB, 0, waveU, lane);
        __syncthreads();
        mfma_lin<F32, false, 32, 256, 128, 264, 136>(HB, 0, Wp1b, wp.p[23], XT, rh, waveU, lane);
        __syncthreads();
    }

    // ---- phase 4: lse2 -> PT ----
    stage_phase<F32, 136, 264>(coords, nidx, wp.p[16], wp.p[17], wp.p[18], wp.p[19],
                               row0, waveU, lane, XT, PT, HB + waveU * 1024);
    __syncthreads();

    // ---- phase 5: p2 (PT -> PT in place), halves ----
#pragma unroll 1
    for (int rh = 0; rh < 64; rh += 32) {
        mfma_lin<F32, true,  32, 256, 256, 264, 264>(PT, rh, Wp2a, wp.p[25], HB, 0, waveU, lane);
        __syncthreads();
        mfma_lin<F32, false, 32, 256, 256, 264, 264>(HB, 0, Wp2b, wp.p[27], PT, rh, waveU, lane);
        __syncthreads();
    }

    // ---- phase 6: leaky(m2(PT) + m3(feats)) -> out, halves ----
#pragma unroll 1
    for (int rh = 0; rh < 64; rh += 32) {
        mfma_lin<F32, true, 32, 256, 384, 264, 392>(PT, rh, Wm2a, wp.p[5], HB, 0, waveU, lane);
        __syncthreads();
        f32x4 acc[16];
#pragma unroll
        for (int n = 0; n < 8; n++) {
            const int col = waveU * 128 + n * 16 + l15;
            const float bb = wld<F32>(wp.p[7], col) + wld<F32>(wp.p[11], col);
            acc[n * 2]     = f32x4{bb, bb, bb, bb};
            acc[n * 2 + 1] = f32x4{bb, bb, bb, bb};
        }
        mfma_acc<384, 512, 392, 2>(HB, Wm2b, acc, waveU, lane);
        __syncthreads();   // HB free

        // stage feats rows rh..rh+32 -> XT[0..32)[136]
        {
            const int t = (int)threadIdx.x;
            const int r = t >> 3, c0 = (t & 7) * 16;
            int rg = row0 + rh + r; if (rg >= NP) rg = NP - 1;
            if constexpr (F32) {
                const float* src = (const float*)feats + (size_t)rg * 128 + c0;
                u32* dst = (u32*)(XT + r * 136 + c0);
#pragma unroll
                for (int q = 0; q < 16; q += 8) {
                    float4 a = *reinterpret_cast<const float4*>(src + q);
                    float4 b = *reinterpret_cast<const float4*>(src + q + 4);
                    dst[(q >> 1) + 0] = packbf2(a.x, a.y); dst[(q >> 1) + 1] = packbf2(a.z, a.w);
                    dst[(q >> 1) + 2] = packbf2(b.x, b.y); dst[(q >> 1) + 3] = packbf2(b.z, b.w);
                }
            } else {
                const u16* src = (const u16*)feats + (size_t)rg * 128 + c0;
                u16* dst = XT + r * 136 + c0;
#pragma unroll
                for (int q = 0; q < 16; q += 8)
                    *reinterpret_cast<uint4*>(dst + q) = *reinterpret_cast<const uint4*>(src + q);
            }
        }
        __syncthreads();
        mfma_lin<F32, true, 32, 128, 256, 136, 264>(XT, 0, Wm3a, wp.p[9], HB, 0, waveU, lane);
        __syncthreads();
        mfma_acc<256, 512, 264, 2>(HB, Wm3b, acc, waveU, lane);

        // leaky + store
#pragma unroll
        for (int n = 0; n < 8; n++) {
#pragma unroll
            for (int m = 0; m < 2; m++) {
#pragma unroll
                for (int r = 0; r < 4; r++) {
                    const int rg = row0 + rh + m * 16 + lhi * 4 + r;
                    if (rg < NP) {
                        const int col = waveU * 128 + n * 16 + l15;
                        float v = acc[n * 2 + m][r];
                        v = v > 0.f ? v : 0.01f * v;
                        if constexpr (F32) ((float*)outp)[(size_t)rg * 512 + col] = v;
                        else               ((u16*)outp)[(size_t)rg * 512 + col] = f2bf(v);
                    }
                }
            }
        }
        __syncthreads();   // XT/HB reuse next half
    }
}

__global__ __launch_bounds__(256, 2) void k_mega_mx(
    const void* __restrict__ coords, const void* __restrict__ feats,
    const int* __restrict__ nidx, WPtrs wp, const u16* __restrict__ ws,
    void* __restrict__ outp)
{
    __shared__ __align__(16) u16 XT[64 * 136];   // 17408 B
    __shared__ __align__(16) u16 PT[64 * 264];   // 33792 B
    __shared__ __align__(16) u16 HB[14336];      // 28672 B
    __shared__ int sflag;

    if (threadIdx.x == 0) {
        const u16* c16 = (const u16*)coords;
        int bad = 0;
        for (int i = 0; i < 128; i++) {
            u32 e = (c16[i] >> 7) & 0xFFu;
            bad += (e != 0u && (e < 63u || e > 191u)) ? 1 : 0;
        }
        sflag = bad;
    }
    __syncthreads();

    if (sflag) run_all_mx<true >(coords, feats, nidx, wp, ws, outp, XT, PT, HB);
    else       run_all_mx<false>(coords, feats, nidx, wp, ws, outp, XT, PT, HB);
}

// ================= weight prepack kernel =================
struct PreDesc { const void* src; int K; int H; int dstOff; int nElems; };
struct PreArr  { PreDesc d[10]; };

__global__ __launch_bounds__(256) void k_prepack(PreArr pa, u16* __restrict__ ws,
                                                 const void* __restrict__ coords)
{
    __shared__ int sflag;
    if (threadIdx.x == 0) {
        const u16* c16 = (const u16*)coords;
        int bad = 0;
        for (int i = 0; i < 128; i++) {
            u32 e = (c16[i] >> 7) & 0xFFu;
            bad += (e != 0u && (e < 63u || e > 191u)) ? 1 : 0;
        }
        sflag = bad;
    }
    __syncthreads();
    const bool F32 = sflag != 0;

    int off = blockIdx.x * 256 + threadIdx.x;
    int m = 0;
#pragma unroll 1
    for (m = 0; m < 10; m++) {
        if (off < pa.d[m].nElems) break;
        off -= pa.d[m].nElems;
    }
    if (m >= 10) return;
    const int H = pa.d[m].H, K32 = pa.d[m].K >> 5;
    const int e = off & 7, lane = (off >> 3) & 63;
    const int r2 = off >> 9;
    const int ks = r2 % K32, n = r2 / K32;
    const int k = ks * 32 + (lane >> 4) * 8 + e;
    const int col = n * 16 + (lane & 15);
    u16 v;
    if (F32) v = f2bf(((const float*)pa.d[m].src)[(size_t)k * H + col]);
    else     v = ((const u16*)pa.d[m].src)[(size_t)k * H + col];
    ws[(size_t)pa.d[m].dstOff + off] = v;
}

// ================= fallback: round-5 scalar kernel (unchanged logic) =================
template<bool WF32, bool INF32, int RW, int CIN, int H>
__device__ __forceinline__ void lin_relu(const void* __restrict__ inb, int SIN,
                                         const void* __restrict__ W1, const void* __restrict__ b1,
                                         u16* __restrict__ outb, int rbIn, int rbOut, int lane)
{
#pragma unroll 1
    for (int c = 0; c < H; c += 128) {
        const int cA = c + lane, cB = c + 64 + lane;
        float aA[RW], aB[RW];
        {
            const float bbA = wld<WF32>(b1, cA), bbB = wld<WF32>(b1, cB);
#pragma unroll
            for (int r = 0; r < RW; r++) { aA[r] = bbA; aB[r] = bbB; }
        }
#pragma unroll 1
        for (int i0 = 0; i0 < CIN; i0 += 8) {
            float wA[8], wB[8];
#pragma unroll
            for (int j = 0; j < 8; j++) {
                wA[j] = wld<WF32>(W1, (i0 + j) * H + cA);
                wB[j] = wld<WF32>(W1, (i0 + j) * H + cB);
            }
#pragma unroll 8
            for (int r = 0; r < RW; r++) {
                float x8[8];
                ldx8<INF32>(inb, (rbIn + r) * SIN + i0, x8);
#pragma unroll
                for (int j = 0; j < 8; j++) {
                    aA[r] = fmaf(x8[j], wA[j], aA[r]);
                    aB[r] = fmaf(x8[j], wB[j], aB[r]);
                }
            }
        }
#pragma unroll
        for (int r = 0; r < RW; r++) {
            outb[(rbOut + r) * H + cA] = f2bf(fmaxf(aA[r], 0.f));
            outb[(rbOut + r) * H + cB] = f2bf(fmaxf(aB[r], 0.f));
        }
    }
}

template<bool WF32, int RW, int HID>
__device__ __forceinline__ void lin_acc2(const u16* __restrict__ hidb, int rb0,
                                         const void* __restrict__ W2, int CO, int cA, int cB,
                                         float* __restrict__ accA, float* __restrict__ accB)
{
#pragma unroll 1
    for (int i0 = 0; i0 < HID; i0 += 8) {
        float wA[8], wB[8];
#pragma unroll
        for (int j = 0; j < 8; j++) {
            wA[j] = wld<WF32>(W2, (i0 + j) * CO + cA);
            wB[j] = wld<WF32>(W2, (i0 + j) * CO + cB);
        }
#pragma unroll 8
        for (int r = 0; r < RW; r++) {
            float x8[8];
            ld8bf(hidb + (rb0 + r) * HID + i0, x8);
#pragma unroll
            for (int j = 0; j < 8; j++) {
                accA[r] = fmaf(x8[j], wA[j], accA[r]);
                accB[r] = fmaf(x8[j], wB[j], accB[r]);
            }
        }
    }
}

template<bool F32>
__device__ __forceinline__ void run_all_fb(
    const void* __restrict__ coords, const void* __restrict__ feats,
    const int* __restrict__ nidx, const WPtrs& wp, void* __restrict__ outp,
    u16* __restrict__ xt, u16* __restrict__ pt, u16* __restrict__ hidb)
{
    const int waveU = __builtin_amdgcn_readfirstlane((int)(threadIdx.x >> 6));
    const int lane  = threadIdx.x & 63;
    const int row0  = blockIdx.x * 64;
    const int rb    = waveU * 16;
    u16* hidw = hidb + waveU * 2048;

    {
        {
            const int r = rb + (lane >> 2), cc = (lane & 3) * 32;
            int rg = row0 + r; if (rg >= NP) rg = NP - 1;
            if constexpr (F32) {
                const float* src = (const float*)feats + (size_t)rg * 128 + cc;
                float* dst = (float*)pt + r * 128 + cc;
#pragma unroll
                for (int q = 0; q < 32; q += 4)
                    *reinterpret_cast<float4*>(dst + q) = *reinterpret_cast<const float4*>(src + q);
            } else {
                const u16* src = (const u16*)feats + (size_t)rg * 128 + cc;
                u16* dst = pt + r * 128 + cc;
#pragma unroll
                for (int q = 0; q < 32; q += 8)
                    *reinterpret_cast<uint4*>(dst + q) = *reinterpret_cast<const uint4*>(src + q);
            }
        }
        LFENCE();
        lin_relu<F32, F32, 16, 128, 128>((const void*)pt, 128, wp.p[0], wp.p[1], hidw, rb, 0, lane);
        LFENCE();
        float accA[16], accB[16];
        {
            const float bA = wld<F32>(wp.p[3], lane), bB = wld<F32>(wp.p[3], 64 + lane);
#pragma unroll
            for (int r = 0; r < 16; r++) { accA[r] = bA; accB[r] = bB; }
        }
        lin_acc2<F32, 16, 128>(hidw, 0, wp.p[2], 128, lane, 64 + lane, accA, accB);
#pragma unroll
        for (int r = 0; r < 16; r++) {
            xt[(rb + r) * 128 + lane]      = f2bf(accA[r]);
            xt[(rb + r) * 128 + 64 + lane] = f2bf(accB[r]);
        }
    }
    __syncthreads();

    stage_phase<F32, 128, 256>(coords, nidx, wp.p[12], wp.p[13], wp.p[14], wp.p[15],
                               row0, waveU, lane, xt, pt, hidw);
    __syncthreads();

#pragma unroll 1
    for (int sh = 0; sh < 16; sh += 8) {
        lin_relu<F32, false, 8, 256, 256>((const void*)pt, 256, wp.p[20], wp.p[21], hidw, rb + sh, 0, lane);
        LFENCE();
        float accA[8], accB[8];
        {
            const float bA = wld<F32>(wp.p[23], lane), bB = wld<F32>(wp.p[23], 64 + lane);
#pragma unroll
            for (int r = 0; r < 8; r++) { accA[r] = bA; accB[r] = bB; }
        }
        lin_acc2<F32, 8, 256>(hidw, 0, wp.p[22], 128, lane, 64 + lane, accA, accB);
#pragma unroll
        for (int r = 0; r < 8; r++) {
            xt[(rb + sh + r) * 128 + lane]      = f2bf(accA[r]);
            xt[(rb + sh + r) * 128 + 64 + lane] = f2bf(accB[r]);
        }
    }
    __syncthreads();

    stage_phase<F32, 128, 256>(coords, nidx, wp.p[16], wp.p[17], wp.p[18], wp.p[19],
                               row0, waveU, lane, xt, pt, hidw);
    __syncthreads();

#pragma unroll 1
    for (int sh = 0; sh < 16; sh += 8) {
        lin_relu<F32, false, 8, 256, 256>((const void*)pt, 256, wp.p[24], wp.p[25], hidw, rb + sh, 0, lane);
        LFENCE();
#pragma unroll 1
        for (int cp = 0; cp < 256; cp += 128) {
            float accA[8], accB[8];
            {
                const float bA = wld<F32>(wp.p[27], cp + lane), bB = wld<F32>(wp.p[27], cp + 64 + lane);
#pragma unroll
                for (int r = 0; r < 8; r++) { accA[r] = bA; accB[r] = bB; }
            }
            lin_acc2<F32, 8, 256>(hidw, 0, wp.p[26], 256, cp + lane, cp + 64 + lane, accA, accB);
#pragma unroll
            for (int r = 0; r < 8; r++) {
                pt[(rb + sh + r) * 256 + cp + lane]      = f2bf(accA[r]);
                pt[(rb + sh + r) * 256 + cp + 64 + lane] = f2bf(accB[r]);
            }
        }
    }
    __syncthreads();

    const int colA = waveU * 128 + lane, colB = colA + 64;
    const float bA6 = wld<F32>(wp.p[7], colA) + wld<F32>(wp.p[11], colA);
    const float bB6 = wld<F32>(wp.p[7], colB) + wld<F32>(wp.p[11], colB);
#pragma unroll 1
    for (int rh = 0; rh < 64; rh += 32) {
        lin_relu<F32, false, 8, 256, 384>((const void*)pt, 256, wp.p[4], wp.p[5],
                                          hidb, rh + waveU * 8, waveU * 8, lane);
        __syncthreads();
#pragma unroll 1
        for (int q = 0; q < 32; q += 16) {
            {
                const int rl = waveU * 4 + (lane >> 4);
                const int cc = (lane & 15) * 8;
                int rg = row0 + rh + q + rl; if (rg >= NP) rg = NP - 1;
                if constexpr (F32) {
                    const float* src = (const float*)feats + (size_t)rg * 128 + cc;
                    float* dst = (float*)xt + rl * 128 + cc;
#pragma unroll
                    for (int u = 0; u < 8; u += 4)
                        *reinterpret_cast<float4*>(dst + u) = *reinterpret_cast<const float4*>(src + u);
                } else {
                    const u16* src = (const u16*)feats + (size_t)rg * 128 + cc;
                    u16* dst = xt + rl * 128 + cc;
                    *reinterpret_cast<uint4*>(dst) = *reinterpret_cast<const uint4*>(src);
                }
            }
            LFENCE();
            lin_relu<F32, F32, 4, 128, 256>((const void*)xt, 128, wp.p[8], wp.p[9],
                                            xt + 4096, waveU * 4, waveU * 4, lane);
            __syncthreads();
            float accA[16], accB[16];
#pragma unroll
            for (int r = 0; r < 16; r++) { accA[r] = bA6; accB[r] = bB6; }
            lin_acc2<F32, 16, 384>(hidb, q, wp.p[6], 512, colA, colB, accA, accB);
            lin_acc2<F32, 16, 256>(xt + 4096, 0, wp.p[10], 512, colA, colB, accA, accB);
#pragma unroll
            for (int r = 0; r < 16; r++) {
                const int rg = row0 + rh + q + r;
                if (rg < NP) {
                    float vA = accA[r]; vA = vA > 0.f ? vA : 0.01f * vA;
                    float vB = accB[r]; vB = vB > 0.f ? vB : 0.01f * vB;
                    if constexpr (F32) {
                        ((float*)outp)[(size_t)rg * 512 + colA] = vA;
                        ((float*)outp)[(size_t)rg * 512 + colB] = vB;
                    } else {
                        ((u16*)outp)[(size_t)rg * 512 + colA] = f2bf(vA);
                        ((u16*)outp)[(size_t)rg * 512 + colB] = f2bf(vB);
                    }
                }
            }
            __syncthreads();
        }
    }
}

__global__ __launch_bounds__(256, 2) void k_mega_fb(
    const void* __restrict__ coords, const void* __restrict__ feats,
    const int* __restrict__ nidx, WPtrs wp, void* __restrict__ outp)
{
    __shared__ __align__(16) u16 xt[64 * 128];
    __shared__ __align__(16) u16 pt[64 * 256];
    __shared__ __align__(16) u16 hidb[12288];
    __shared__ int sflag;

    if (threadIdx.x == 0) {
        const u16* c16 = (const u16*)coords;
        int bad = 0;
        for (int i = 0; i < 128; i++) {
            u32 e = (c16[i] >> 7) & 0xFFu;
            bad += (e != 0u && (e < 63u || e > 191u)) ? 1 : 0;
        }
        sflag = bad;
    }
    __syncthreads();

    if (sflag) run_all_fb<true >(coords, feats, nidx, wp, outp, xt, pt, hidb);
    else       run_all_fb<false>(coords, feats, nidx, wp, outp, xt, pt, hidb);
}

// ---------------- host ----------------
extern "C" void kernel_launch(void* const* d_in, const int* in_sizes, int n_in,
                              void* d_out, int out_size, void* d_ws, size_t ws_size,
                              hipStream_t stream)
{
    const void* coords = d_in[0];
    const void* feats  = d_in[1];
    const int*  nidx   = (const int*)d_in[2];

    WPtrs wp;
    for (int i = 0; i < 28; i++) wp.p[i] = d_in[3 + i];
    // p[0..3]=m1, p[4..7]=m2, p[8..11]=m3, p[12..15]=l1, p[16..19]=l2, p[20..23]=p1, p[24..27]=p2

    static const int KK[10]  = {128, 128, 256, 384, 128, 256, 256, 256, 256, 256};
    static const int HH[10]  = {128, 128, 384, 512, 256, 512, 256, 128, 256, 256};
    static const int SRC[10] = {0, 2, 4, 6, 8, 10, 20, 22, 24, 26};
    PreArr pa;
    int off = 0;
    for (int i = 0; i < 10; i++) {
        pa.d[i].src = d_in[3 + SRC[i]];
        pa.d[i].K = KK[i]; pa.d[i].H = HH[i];
        pa.d[i].dstOff = off; pa.d[i].nElems = KK[i] * HH[i];
        off += KK[i] * HH[i];
    }
    const size_t WS_NEED = (size_t)off * 2;   // 1,441,792 B

    if (d_ws != nullptr && ws_size >= WS_NEED) {
        const int total = off;                 // 720,896 threads
        k_prepack<<<(total + 255) / 256, 256, 0, stream>>>(pa, (u16*)d_ws, coords);
        k_mega_mx<<<(NP + 63) / 64, 256, 0, stream>>>(coords, feats, nidx, wp,
                                                      (const u16*)d_ws, d_out);
    } else {
        k_mega_fb<<<(NP + 63) / 64, 256, 0, stream>>>(coords, feats, nidx, wp, d_out);
    }
}